// Round 1
// baseline (867.009 us; speedup 1.0000x reference)
//
#include <hip/hip_runtime.h>
#include <hip/hip_bf16.h>

#define IN_CH 128
#define HID 64
#define NEG_SLOPE 0.2f

// ---------------------------------------------------------------------------
// h = x @ W  (fp32, vector ALU — no fp32 MFMA on CDNA4)
// also a_src[n] = h[n]·att_src, a_dst[n] = h[n]·att_dst via wave reduction.
// Block = 256 threads = 4 waves; lane = output channel c (64 ch); each wave
// handles 4 nodes; block handles 16 nodes. W staged in LDS (32 KB), x rows
// staged in LDS (8 KB). W reads: 64 consecutive floats -> 2-way bank alias
// (free); x reads: wave-uniform broadcast (free).
// ---------------------------------------------------------------------------
__global__ __launch_bounds__(256) void k_gemm(
    const float* __restrict__ x, const float* __restrict__ W,
    const float* __restrict__ att_src, const float* __restrict__ att_dst,
    float* __restrict__ h, float* __restrict__ a_src, float* __restrict__ a_dst,
    int N)
{
    __shared__ float sW[IN_CH * HID];     // 32 KB, layout [k][c]
    __shared__ float sx[16][IN_CH];       // 8 KB
    const int t = threadIdx.x;
    const int nb = blockIdx.x * 16;

    // stage W: 8192 floats = 2048 float4
    {
        const float4* Wv = (const float4*)W;
        float4* sWv = (float4*)sW;
        for (int i = t; i < IN_CH * HID / 4; i += 256) sWv[i] = Wv[i];
    }
    // stage 16 x rows: 2048 floats = 512 float4
    {
        const float4* xv = (const float4*)x;
        float4* sxv = (float4*)&sx[0][0];
        for (int i = t; i < 512; i += 256) {
            int node = nb + (i >> 5);          // 32 float4 per row
            int kk = i & 31;
            float4 v = make_float4(0.f, 0.f, 0.f, 0.f);
            if (node < N) v = xv[node * (IN_CH / 4) + kk];
            sxv[i] = v;
        }
    }
    __syncthreads();

    const int wave = t >> 6;
    const int c = t & 63;
    const int s0 = wave * 4;

    float acc0 = 0.f, acc1 = 0.f, acc2 = 0.f, acc3 = 0.f;
#pragma unroll
    for (int k = 0; k < IN_CH; k += 4) {
        float4 x0 = *(const float4*)&sx[s0 + 0][k];
        float4 x1 = *(const float4*)&sx[s0 + 1][k];
        float4 x2 = *(const float4*)&sx[s0 + 2][k];
        float4 x3 = *(const float4*)&sx[s0 + 3][k];
        float w0 = sW[(k + 0) * HID + c];
        float w1 = sW[(k + 1) * HID + c];
        float w2 = sW[(k + 2) * HID + c];
        float w3 = sW[(k + 3) * HID + c];
        acc0 = fmaf(x0.x, w0, fmaf(x0.y, w1, fmaf(x0.z, w2, fmaf(x0.w, w3, acc0))));
        acc1 = fmaf(x1.x, w0, fmaf(x1.y, w1, fmaf(x1.z, w2, fmaf(x1.w, w3, acc1))));
        acc2 = fmaf(x2.x, w0, fmaf(x2.y, w1, fmaf(x2.z, w2, fmaf(x2.w, w3, acc2))));
        acc3 = fmaf(x3.x, w0, fmaf(x3.y, w1, fmaf(x3.z, w2, fmaf(x3.w, w3, acc3))));
    }

    const float as_c = att_src[c];
    const float ad_c = att_dst[c];
    float accs[4] = {acc0, acc1, acc2, acc3};
#pragma unroll
    for (int j = 0; j < 4; ++j) {
        int node = nb + s0 + j;
        if (node < N) h[node * HID + c] = accs[j];
        float ps = accs[j] * as_c;
        float pd = accs[j] * ad_c;
#pragma unroll
        for (int m = 32; m > 0; m >>= 1) {
            ps += __shfl_xor(ps, m, 64);
            pd += __shfl_xor(pd, m, 64);
        }
        if (c == 0 && node < N) { a_src[node] = ps; a_dst[node] = pd; }
    }
}

// ---------------------------------------------------------------------------
__global__ void k_zero(int* __restrict__ p, int n)
{
    int i = blockIdx.x * 256 + threadIdx.x;
    if (i < n) p[i] = 0;
}

// count in-degree (dst) including self loops appended after the E real edges
__global__ void k_count(const int* __restrict__ ei, int* __restrict__ cnt,
                        int E, int N)
{
    int e = blockIdx.x * 256 + threadIdx.x;
    if (e >= E + N) return;
    int d = (e < E) ? ei[E + e] : (e - E);
    atomicAdd(&cnt[d], 1);
}

// hierarchical exclusive scan over cnt[N]
__global__ __launch_bounds__(1024) void k_scan1(const int* __restrict__ cnt,
                                                int* __restrict__ incl,
                                                int* __restrict__ part, int N)
{
    __shared__ int sh[1024];
    int t = threadIdx.x;
    int i = blockIdx.x * 1024 + t;
    int v = (i < N) ? cnt[i] : 0;
#pragma unroll
    for (int off = 1; off < 1024; off <<= 1) {
        sh[t] = v;
        __syncthreads();
        if (t >= off) v += sh[t - off];
        __syncthreads();
    }
    if (i < N) incl[i] = v;
    if (t == 1023) part[blockIdx.x] = v;
}

__global__ __launch_bounds__(64) void k_scan2(int* __restrict__ part, int nchunks)
{
    int l = threadIdx.x;
    int o0 = (l < nchunks) ? part[l] : 0;
    int o1 = (64 + l < nchunks) ? part[64 + l] : 0;
    int v0 = o0, v1 = o1;
#pragma unroll
    for (int off = 1; off < 64; off <<= 1) {
        int u = __shfl_up(v0, off, 64);
        if (l >= off) v0 += u;
    }
    int tot0 = __shfl(v0, 63, 64);
#pragma unroll
    for (int off = 1; off < 64; off <<= 1) {
        int u = __shfl_up(v1, off, 64);
        if (l >= off) v1 += u;
    }
    if (l < nchunks) part[l] = v0 - o0;                 // exclusive
    if (64 + l < nchunks) part[64 + l] = tot0 + v1 - o1;
}

__global__ __launch_bounds__(1024) void k_scan3(const int* __restrict__ incl,
                                                const int* __restrict__ cnt,
                                                const int* __restrict__ part,
                                                int* __restrict__ row_start,
                                                int* __restrict__ cur, int N)
{
    int i = blockIdx.x * 1024 + threadIdx.x;
    if (i >= N) return;
    int r = incl[i] - cnt[i] + part[blockIdx.x];
    row_start[i] = r;
    cur[i] = r;
}

// scatter edges into CSR order (by dst), remembering src and original edge id
__global__ void k_fill(const int* __restrict__ ei, int* __restrict__ cur,
                       int* __restrict__ csr_src, int* __restrict__ csr_eid,
                       int E, int N)
{
    int e = blockIdx.x * 256 + threadIdx.x;
    if (e >= E + N) return;
    int s = (e < E) ? ei[e] : (e - E);
    int d = (e < E) ? ei[E + e] : (e - E);
    int pos = atomicAdd(&cur[d], 1);
    csr_src[pos] = s;
    csr_eid[pos] = e;
}

// ---------------------------------------------------------------------------
// wave-per-dst: softmax denominator (max-pass elided; logits are O(8)) then
// alpha write + weighted aggregation of h[src] rows. lane = channel.
// ---------------------------------------------------------------------------
__global__ __launch_bounds__(256) void k_agg(
    const float* __restrict__ h, const float* __restrict__ a_src,
    const float* __restrict__ a_dst, const float* __restrict__ bias,
    const int* __restrict__ row_start, const int* __restrict__ cnt,
    const int* __restrict__ csr_src, const int* __restrict__ csr_eid,
    float* __restrict__ out, float* __restrict__ out_alpha, int N)
{
    const int wave = threadIdx.x >> 6;
    const int lane = threadIdx.x & 63;
    const int d = blockIdx.x * 4 + wave;
    if (d >= N) return;

    const float ad = a_dst[d];
    const int start = row_start[d];
    const int n = cnt[d];
    const int end = start + n;

    // pass 1: sum of exp(leaky(logit)) across incoming edges (lane-parallel)
    float psum = 0.f;
    for (int b = start; b < end; b += 64) {
        int idx = b + lane;
        if (idx < end) {
            int s = csr_src[idx];
            float v = a_src[s] + ad;
            v = v > 0.f ? v : NEG_SLOPE * v;
            psum += __expf(v);
        }
    }
#pragma unroll
    for (int m = 32; m > 0; m >>= 1) psum += __shfl_xor(psum, m, 64);
    const float inv = 1.0f / psum;   // n>=1 guaranteed by self loops

    // pass 2: alpha write + aggregation
    float acc = 0.f;
    for (int b = start; b < end; b += 64) {
        int idx = b + lane;
        int s = 0;
        float alpha = 0.f;
        int m = min(64, end - b);
        if (idx < end) {
            s = csr_src[idx];
            int eid = csr_eid[idx];
            float v = a_src[s] + ad;
            v = v > 0.f ? v : NEG_SLOPE * v;
            alpha = __expf(v) * inv;
            out_alpha[eid] = alpha;
        }
        for (int j = 0; j < m; ++j) {
            int sj = __shfl(s, j, 64);
            float aj = __shfl(alpha, j, 64);
            acc = fmaf(aj, h[sj * HID + lane], acc);
        }
    }
    out[d * HID + lane] = acc + bias[lane];
}

// ---------------------------------------------------------------------------
extern "C" void kernel_launch(void* const* d_in, const int* in_sizes, int n_in,
                              void* d_out, int out_size, void* d_ws, size_t ws_size,
                              hipStream_t stream)
{
    (void)n_in; (void)out_size; (void)ws_size;
    const float* x       = (const float*)d_in[0];
    const int*   ei      = (const int*)d_in[1];
    const float* W       = (const float*)d_in[2];
    const float* att_src = (const float*)d_in[3];
    const float* att_dst = (const float*)d_in[4];
    const float* bias    = (const float*)d_in[5];

    const int N = in_sizes[0] / IN_CH;   // 100000
    const int E = in_sizes[1] / 2;       // 3200000
    const int T = E + N;                 // edges incl. self loops

    // workspace layout
    float* h       = (float*)d_ws;                 // N*HID
    float* a_src_d = h + (size_t)N * HID;          // N
    float* a_dst_d = a_src_d + N;                  // N
    int* cnt       = (int*)(a_dst_d + N);          // N
    int* incl      = cnt + N;                      // N
    int* row_start = incl + N;                     // N
    int* cur       = row_start + N;                // N
    int* part      = cur + N;                      // 128
    int* csr_src   = part + 128;                   // T
    int* csr_eid   = csr_src + T;                  // T

    float* out       = (float*)d_out;              // N*HID
    float* out_alpha = out + (size_t)N * HID;      // T

    const int nch = (N + 1023) / 1024;             // 98

    k_gemm<<<(N + 15) / 16, 256, 0, stream>>>(x, W, att_src, att_dst,
                                              h, a_src_d, a_dst_d, N);
    k_zero<<<(N + 255) / 256, 256, 0, stream>>>(cnt, N);
    k_count<<<(T + 255) / 256, 256, 0, stream>>>(ei, cnt, E, N);
    k_scan1<<<nch, 1024, 0, stream>>>(cnt, incl, part, N);
    k_scan2<<<1, 64, 0, stream>>>(part, nch);
    k_scan3<<<nch, 1024, 0, stream>>>(incl, cnt, part, row_start, cur, N);
    k_fill<<<(T + 255) / 256, 256, 0, stream>>>(ei, cur, csr_src, csr_eid, E, N);
    k_agg<<<(N + 3) / 4, 256, 0, stream>>>(h, a_src_d, a_dst_d, bias,
                                           row_start, cnt, csr_src, csr_eid,
                                           out, out_alpha, N);
}